// Round 13
// baseline (95.137 us; speedup 1.0000x reference)
//
#include <hip/hip_runtime.h>

// DSAttention forward, MI355X gfx950.
// B=2, L=S=2048, H=16, E=D=64. fp32 in/out, fp16 MFMA compute.
//
// Round 12 (v6): v5 + XCD-aware block mapping. Grid flattened to 512 blocks;
// block i -> XCD i&7 (empirical round-robin, m157/m192); XCD j serves
// bh in {4j..4j+3}, so each XCD's K/V working set is 2MB (< 4MB L2).
// Kernel body otherwise identical to v5 (split-S, 8 waves, 2-phase staging).

#define Bb 2
#define Ll 2048
#define Ss 2048
#define Hh 16
#define Ee 64
#define Dd 64
#define KV 64

typedef _Float16 f16x8 __attribute__((ext_vector_type(8)));
typedef _Float16 f16x4 __attribute__((ext_vector_type(4)));
typedef __fp16 fp16x2 __attribute__((ext_vector_type(2)));
typedef float f32x4 __attribute__((ext_vector_type(4)));

union Pk2 { fp16x2 h; unsigned u; };
union PackU { unsigned u[4]; f16x8 v; };

#define GLDS(gp, lp) __builtin_amdgcn_global_load_lds( \
    (const __attribute__((address_space(1))) void*)(gp), \
    (__attribute__((address_space(3))) void*)(lp), 16, 0, 0)

// -------- pre-pass: K fp32 [B,S,H,E] -> fp16 [B,H,S,E]; delta2 = 0.125*delta --------
__global__ __launch_bounds__(256)
void prepass_k(const float* __restrict__ K, _Float16* __restrict__ K16,
               const float* __restrict__ delta, float* __restrict__ delta2)
{
    const unsigned v = blockIdx.x * 256 + threadIdx.x;   // float4 id, 1M total
    const unsigned e4 = v & 15;
    const unsigned h  = (v >> 4) & 15;
    const unsigned s  = (v >> 8) & (Ss - 1);
    const unsigned b  = v >> 19;
    const f32x4 src = ((const f32x4*)K)[v];
    f16x4 t;
    t[0] = (_Float16)src[0]; t[1] = (_Float16)src[1];
    t[2] = (_Float16)src[2]; t[3] = (_Float16)src[3];
    ((f16x4*)K16)[(((size_t)(b * Hh + h) * Ss + s) * 16) + e4] = t;
    if (v < (Bb * Ss) / 4) {
        f32x4 dd = ((const f32x4*)delta)[v];
        ((f32x4*)delta2)[v] = (f32x4){0.125f * dd[0], 0.125f * dd[1],
                                      0.125f * dd[2], 0.125f * dd[3]};
    }
}

// ------------- pre-pass: V fp32 [B,S,H,D] -> fp16 transposed [B,H,D,S] -------------
__global__ __launch_bounds__(256)
void prepass_v(const float* __restrict__ V, _Float16* __restrict__ VT16)
{
    __shared__ _Float16 TL[64][66];
    const int tid  = threadIdx.x;
    const int wave = tid >> 6;
    const int lane = tid & 63;
    const int bh = blockIdx.y;
    const int b  = bh >> 4;
    const int h  = bh & 15;
    const int s0 = blockIdx.x * 64;

    #pragma unroll
    for (int rr = 0; rr < 16; ++rr) {
        const int row = wave * 16 + rr;
        TL[row][lane] = (_Float16)V[((size_t)(b * Ss + s0 + row) * Hh + h) * Dd + lane];
    }
    __syncthreads();
    const int d  = tid >> 2;
    const int sq = (tid & 3) * 16;
    union { _Float16 h[16]; f16x8 v[2]; } tmp;
    #pragma unroll
    for (int i = 0; i < 16; ++i) tmp.h[i] = TL[sq + i][d];
    f16x8* dp = (f16x8*)(VT16 + ((size_t)(b * Hh + h) * Dd + d) * Ss + s0 + sq);
    dp[0] = tmp.v[0];
    dp[1] = tmp.v[1];
}

// ---------------------------- main kernel (v6) ----------------------------
__global__ __launch_bounds__(512)
void dsattn_fwd_v6(const float* __restrict__ Q, const _Float16* __restrict__ K16,
                   const _Float16* __restrict__ VT16, const float* __restrict__ tau,
                   const float* __restrict__ delta2, float* __restrict__ out)
{
    // dynamic LDS, 65536 B:
    //   half H at H*32768: buf c at +c*16384 (K tile 8KB, V tile at +8192)
    //   epilogue: Part [4][2][16][68] f32 at 0, then Osm [128][68] at 0
    extern __shared__ __align__(16) unsigned char smem[];

    const int tid  = threadIdx.x;
    const int wave = tid >> 6;        // 0..7
    const int half = wave >> 2;       // s-half
    const int wq   = wave & 3;        // q-quarter within block
    const int lane = tid & 63;
    const int lq   = lane & 15;
    const int g    = lane >> 4;
    const int tid_h = tid & 255;      // id within the half's staging group

    // XCD-aware decode: block i -> XCD i&7; XCD j owns bh {4j..4j+3}.
    const int bid = blockIdx.x;       // 0..511
    const int xcd = bid & 7;
    const int kk  = bid >> 3;         // 0..63
    const int bh  = xcd * 4 + (kk & 3);
    const int b   = bh >> 4;
    const int h   = bh & 15;
    const int q0  = (kk >> 2) * 128;  // q-block 0..15
    const int qw  = q0 + wq * 32;     // wave covers 32 q (2 groups of 16)

    const float alpha = 0.125f * tau[b];

    // Q fragments: aq[qg][es], lane holds Q[qw+qg*16+lq][es*32 + g*8 + j]
    f16x8 aq[2][2];
    #pragma unroll
    for (int qg = 0; qg < 2; ++qg) {
        const float* qp = Q + (((size_t)b * Ll + qw + qg * 16 + lq) * Hh + h) * Ee;
        #pragma unroll
        for (int es = 0; es < 2; ++es) {
            const float* p = qp + es * 32 + g * 8;
            f16x8 t;
            #pragma unroll
            for (int j = 0; j < 8; ++j) t[j] = (_Float16)p[j];
            aq[qg][es] = t;
        }
    }

    f32x4 osum[2][4];
    #pragma unroll
    for (int qg = 0; qg < 2; ++qg)
        #pragma unroll
        for (int i = 0; i < 4; ++i) osum[qg][i] = (f32x4){0.f, 0.f, 0.f, 0.f};
    float m_run[2] = {-1e30f, -1e30f};
    float l_run[2] = {0.0f, 0.0f};

    const unsigned char* kb  = (const unsigned char*)(K16 + (size_t)(b * Hh + h) * Ss * Ee);
    const unsigned char* vtb = (const unsigned char*)(VT16 + (size_t)(b * Hh + h) * Dd * Ss);
    const float* d2b = delta2 + (size_t)b * Ss;

    const int row0  = tid_h >> 3;                     // 0..31; issue 1 = +32
    const int slotS = (tid_h & 7) ^ (row0 & 7);
    unsigned char* stBase = smem + half * 32768;      // this half's staging region
    const int sBase = half * (Ss / 2);                // this half's s origin

    // ---- prologue: stage tile 0 into buf 0; load delta regs for tile 0 ----
    {
        unsigned char* kw = stBase + wq * 1024;
        unsigned char* vw = stBase + 8192 + wq * 1024;
        GLDS(kb + (size_t)(sBase + row0) * 128 + slotS * 16,        kw);
        GLDS(kb + (size_t)(sBase + row0 + 32) * 128 + slotS * 16,   kw + 4096);
        GLDS(vtb + (size_t)row0 * (Ss * 2) + sBase * 2 + slotS * 16,        vw);
        GLDS(vtb + (size_t)(row0 + 32) * (Ss * 2) + sBase * 2 + slotS * 16, vw + 4096);
    }
    f32x4 dcur[4], dnxt[4];
    #pragma unroll
    for (int t = 0; t < 4; ++t)
        dcur[t] = *(const f32x4*)(d2b + sBase + t * 16 + 4 * g);
    __syncthreads();   // buf0 ready (both halves)

    const int srcA = lq + 32 * (g & 1);
    const int srcB = srcA + 16;
    const bool gh = (g >> 1);

    int cur = 0;
    for (int it = 0; it < Ss / 2 / KV; ++it) {
        const int sb = sBase + it * KV;
        const int nb = (it + 1 < Ss / 2 / KV);
        // ---- stage next tile into buf^1 (in flight during compute) ----
        if (nb) {
            unsigned char* kw = stBase + (cur ^ 1) * 16384 + wq * 1024;
            unsigned char* vw = kw + 8192;
            const int sn = sb + KV;
            GLDS(kb + (size_t)(sn + row0) * 128 + slotS * 16,        kw);
            GLDS(kb + (size_t)(sn + row0 + 32) * 128 + slotS * 16,   kw + 4096);
            GLDS(vtb + (size_t)row0 * (Ss * 2) + sn * 2 + slotS * 16,        vw);
            GLDS(vtb + (size_t)(row0 + 32) * (Ss * 2) + sn * 2 + slotS * 16, vw + 4096);
        }
        {   // prefetch next delta regs
            const int sn = nb ? sb + KV : sb;
            #pragma unroll
            for (int t = 0; t < 4; ++t)
                dnxt[t] = *(const f32x4*)(d2b + sn + t * 16 + 4 * g);
        }

        const unsigned char* Ksm = stBase + cur * 16384;
        const unsigned char* Vsm = Ksm + 8192;

        // ---- QK^T for both q-groups, sharing each K fragment read ----
        f32x4 c4[2][4];
        #pragma unroll
        for (int qg = 0; qg < 2; ++qg)
            #pragma unroll
            for (int t = 0; t < 4; ++t) c4[qg][t] = (f32x4){0.f, 0.f, 0.f, 0.f};
        __builtin_amdgcn_s_setprio(1);
        #pragma unroll
        for (int t = 0; t < 4; ++t) {
            const int srow = t * 16 + lq;
            #pragma unroll
            for (int es = 0; es < 2; ++es) {
                const int slot = (es * 4 + g) ^ (srow & 7);
                f16x8 ak = *(const f16x8*)(Ksm + srow * 128 + slot * 16);
                c4[0][t] = __builtin_amdgcn_mfma_f32_16x16x32_f16(ak, aq[0][es], c4[0][t], 0, 0, 0);
                c4[1][t] = __builtin_amdgcn_mfma_f32_16x16x32_f16(ak, aq[1][es], c4[1][t], 0, 0, 0);
            }
        }
        __builtin_amdgcn_s_setprio(0);

        // ---- per q-group: softmax (defer-max) + pack + PV B-frags ----
        PackU bp[2][2];
        #pragma unroll
        for (int qg = 0; qg < 2; ++qg) {
            float p[16];
            float tmax = -1e30f;
            #pragma unroll
            for (int t = 0; t < 4; ++t)
                #pragma unroll
                for (int j = 0; j < 4; ++j) {
                    float z = fmaf(alpha, c4[qg][t][j], dcur[t][j]);
                    p[t * 4 + j] = z;
                    tmax = fmaxf(tmax, z);
                }
            tmax = fmaxf(tmax, __shfl_xor(tmax, 16));
            tmax = fmaxf(tmax, __shfl_xor(tmax, 32));
            if (!__all(tmax <= m_run[qg] + 8.0f)) {
                const float m_new = fmaxf(m_run[qg], tmax);
                const float corr  = __expf(m_run[qg] - m_new);
                l_run[qg] *= corr;
                #pragma unroll
                for (int dt = 0; dt < 4; ++dt)
                    #pragma unroll
                    for (int j = 0; j < 4; ++j)
                        osum[qg][dt][j] *= corr;
                m_run[qg] = m_new;
            }
            float psum = 0.f;
            #pragma unroll
            for (int i = 0; i < 16; ++i) { p[i] = __expf(p[i] - m_run[qg]); psum += p[i]; }
            psum += __shfl_xor(psum, 16);
            psum += __shfl_xor(psum, 32);
            l_run[qg] += psum;

            unsigned pk[8];
            #pragma unroll
            for (int t = 0; t < 4; ++t) {
                Pk2 u0, u1;
                u0.h = __builtin_amdgcn_cvt_pkrtz(p[4 * t], p[4 * t + 1]);
                u1.h = __builtin_amdgcn_cvt_pkrtz(p[4 * t + 2], p[4 * t + 3]);
                pk[t * 2] = u0.u;
                pk[t * 2 + 1] = u1.u;
            }
            #pragma unroll
            for (int ks = 0; ks < 2; ++ks) {
                unsigned a0 = __shfl(pk[ks * 4 + 0], srcA), a1 = __shfl(pk[ks * 4 + 1], srcA);
                unsigned a2 = __shfl(pk[ks * 4 + 2], srcA), a3 = __shfl(pk[ks * 4 + 3], srcA);
                unsigned b0 = __shfl(pk[ks * 4 + 0], srcB), b1 = __shfl(pk[ks * 4 + 1], srcB);
                unsigned b2 = __shfl(pk[ks * 4 + 2], srcB), b3 = __shfl(pk[ks * 4 + 3], srcB);
                bp[qg][ks].u[0] = gh ? a2 : a0;
                bp[qg][ks].u[1] = gh ? a3 : a1;
                bp[qg][ks].u[2] = gh ? b2 : b0;
                bp[qg][ks].u[3] = gh ? b3 : b1;
            }
        }

        // ---- PV for both q-groups, sharing each V fragment read ----
        __builtin_amdgcn_s_setprio(1);
        #pragma unroll
        for (int ks = 0; ks < 2; ++ks)
            #pragma unroll
            for (int dt = 0; dt < 4; ++dt) {
                const int vrow = dt * 16 + lq;
                const int slot = (ks * 4 + g) ^ (vrow & 7);
                f16x8 av = *(const f16x8*)(Vsm + vrow * 128 + slot * 16);
                osum[0][dt] = __builtin_amdgcn_mfma_f32_16x16x32_f16(av, bp[0][ks].v, osum[0][dt], 0, 0, 0);
                osum[1][dt] = __builtin_amdgcn_mfma_f32_16x16x32_f16(av, bp[1][ks].v, osum[1][dt], 0, 0, 0);
            }
        __builtin_amdgcn_s_setprio(0);

        __syncthreads();   // next-tile GLDS drained; all waves done with buf[cur]
        cur ^= 1;
        #pragma unroll
        for (int t = 0; t < 4; ++t) dcur[t] = dnxt[t];
    }

    // ---- epilogue: flash-combine the two s-halves, then coalesced store ----
    float (*Part)[2][16][68] = (float (*)[2][16][68])smem;   // [4][2][16][68]
    if (half == 1) {
        #pragma unroll
        for (int qg = 0; qg < 2; ++qg) {
            #pragma unroll
            for (int dt = 0; dt < 4; ++dt)
                *(f32x4*)&Part[wq][qg][lq][dt * 16 + 4 * g] = osum[qg][dt];
            if (g == 0) {
                Part[wq][qg][lq][64] = m_run[qg];
                Part[wq][qg][lq][65] = l_run[qg];
            }
        }
    }
    __syncthreads();
    if (half == 0) {
        #pragma unroll
        for (int qg = 0; qg < 2; ++qg) {
            const float m1 = Part[wq][qg][lq][64];
            const float l1 = Part[wq][qg][lq][65];
            const float m  = fmaxf(m_run[qg], m1);
            const float s0 = __expf(m_run[qg] - m);
            const float s1 = __expf(m1 - m);
            const float inv = 1.0f / (l_run[qg] * s0 + l1 * s1);
            #pragma unroll
            for (int dt = 0; dt < 4; ++dt) {
                f32x4 p1 = *(const f32x4*)&Part[wq][qg][lq][dt * 16 + 4 * g];
                #pragma unroll
                for (int j = 0; j < 4; ++j)
                    osum[qg][dt][j] = (osum[qg][dt][j] * s0 + p1[j] * s1) * inv;
            }
        }
    }
    __syncthreads();   // all Part reads done; smem reusable
    float (*Osm)[68] = (float (*)[68])smem;                  // [128][68]
    if (half == 0) {
        #pragma unroll
        for (int qg = 0; qg < 2; ++qg)
            #pragma unroll
            for (int dt = 0; dt < 4; ++dt)
                *(f32x4*)&Osm[wq * 32 + qg * 16 + lq][dt * 16 + 4 * g] = osum[qg][dt];
    }
    __syncthreads();
    {
        float* ob = out + (((size_t)b * Ll + q0) * Hh + h) * Dd;
        #pragma unroll
        for (int i = 0; i < 16; ++i) {
            const int r = wave * 16 + i;
            ob[(size_t)r * (Hh * Dd) + lane] = Osm[r][lane];
        }
    }
}

// ---------------------------- fallback (v1, verified r5) ----------------------------
__global__ __launch_bounds__(256)
void dsattn_fwd(const float* __restrict__ Q, const float* __restrict__ K,
                const float* __restrict__ V, const float* __restrict__ tau,
                const float* __restrict__ delta, float* __restrict__ out)
{
    __shared__ __align__(16) unsigned char Ksm[32 * 128];
    __shared__ __align__(16) unsigned char VTsm[64 * 80];
    __shared__ float dsm[32];
    __shared__ float Osm[4][16][68];

    const int tid  = threadIdx.x;
    const int wave = tid >> 6;
    const int lane = tid & 63;
    const int lq   = lane & 15;
    const int g    = lane >> 4;

    const int bh = blockIdx.y;
    const int b  = bh >> 4;
    const int h  = bh & 15;
    const int q0 = blockIdx.x * 64;

    const float alpha = 0.125f * tau[b];

    f16x8 aq[2];
    {
        const float* qp = Q + (((long)b * Ll + q0 + wave * 16 + lq) * Hh + h) * Ee;
        #pragma unroll
        for (int es = 0; es < 2; ++es) {
            const float* p = qp + es * 32 + g * 8;
            f16x8 t;
            #pragma unroll
            for (int j = 0; j < 8; ++j) t[j] = (_Float16)p[j];
            aq[es] = t;
        }
    }

    f32x4 osum[4];
    #pragma unroll
    for (int i = 0; i < 4; ++i) osum[i] = (f32x4){0.f, 0.f, 0.f, 0.f};
    float m_run = -1e30f, l_run = 0.0f;

    const float* kb = K + ((long)b * Ss * Hh + h) * Ee;
    const float* vb = V + ((long)b * Ss * Hh + h) * Dd;
    const float* db = delta + (long)b * Ss;

    const int kr    = tid >> 3;
    const int kc    = (tid & 7) * 8;
    const int kslot = (((tid & 7) ^ (kr & 7)) * 16);
    const int vd    = tid & 63;
    const int vsh   = tid >> 6;

    for (int sb = 0; sb < Ss; sb += 32) {
        __syncthreads();
        {
            const float* src = kb + (long)(sb + kr) * (Hh * Ee) + kc;
            f16x8 t;
            #pragma unroll
            for (int j = 0; j < 8; ++j) t[j] = (_Float16)src[j];
            *(f16x8*)(Ksm + kr * 128 + kslot) = t;
        }
        {
            const float* src = vb + (long)(sb + vsh * 8) * (Hh * Dd) + vd;
            f16x8 t;
            #pragma unroll
            for (int j = 0; j < 8; ++j) t[j] = (_Float16)src[j * (Hh * Dd)];
            *(f16x8*)(VTsm + vd * 80 + vsh * 16) = t;
        }
        if (tid < 32) dsm[tid] = 0.125f * db[sb + tid];
        __syncthreads();

        float p[8];
        float tmax = -1e30f;
        #pragma unroll
        for (int t = 0; t < 2; ++t) {
            f32x4 c = (f32x4){0.f, 0.f, 0.f, 0.f};
            #pragma unroll
            for (int es = 0; es < 2; ++es) {
                const int srow = t * 16 + lq;
                const int slot = ((es * 4 + g) ^ (srow & 7)) * 16;
                f16x8 ak = *(const f16x8*)(Ksm + srow * 128 + slot);
                c = __builtin_amdgcn_mfma_f32_16x16x32_f16(ak, aq[es], c, 0, 0, 0);
            }
            #pragma unroll
            for (int j = 0; j < 4; ++j) {
                float z = alpha * c[j] + dsm[t * 16 + 4 * g + j];
                p[t * 4 + j] = z;
                tmax = fmaxf(tmax, z);
            }
        }
        tmax = fmaxf(tmax, __shfl_xor(tmax, 16));
        tmax = fmaxf(tmax, __shfl_xor(tmax, 32));
        const float m_new = fmaxf(m_run, tmax);
        const float corr  = __expf(m_run - m_new);
        float psum = 0.f;
        #pragma unroll
        for (int i = 0; i < 8; ++i) { p[i] = __expf(p[i] - m_new); psum += p[i]; }
        psum += __shfl_xor(psum, 16);
        psum += __shfl_xor(psum, 32);
        l_run = l_run * corr + psum;
        m_run = m_new;
        #pragma unroll
        for (int dt = 0; dt < 4; ++dt)
            #pragma unroll
            for (int j = 0; j < 4; ++j)
                osum[dt][j] *= corr;

        Pk2 u00, u01, u10, u11;
        u00.h = __builtin_amdgcn_cvt_pkrtz(p[0], p[1]);
        u01.h = __builtin_amdgcn_cvt_pkrtz(p[2], p[3]);
        u10.h = __builtin_amdgcn_cvt_pkrtz(p[4], p[5]);
        u11.h = __builtin_amdgcn_cvt_pkrtz(p[6], p[7]);
        const int srcA = lq + 32 * (g & 1);
        const int srcB = srcA + 16;
        unsigned a00 = __shfl(u00.u, srcA), a01 = __shfl(u01.u, srcA);
        unsigned a10 = __shfl(u10.u, srcA), a11 = __shfl(u11.u, srcA);
        unsigned b00 = __shfl(u00.u, srcB), b01 = __shfl(u01.u, srcB);
        unsigned b10 = __shfl(u10.u, srcB), b11 = __shfl(u11.u, srcB);
        const bool hi = (g >= 2);
        PackU bp;
        bp.u[0] = hi ? a10 : a00;
        bp.u[1] = hi ? a11 : a01;
        bp.u[2] = hi ? b10 : b00;
        bp.u[3] = hi ? b11 : b01;

        #pragma unroll
        for (int dt = 0; dt < 4; ++dt) {
            f16x8 av = *(const f16x8*)(VTsm + (dt * 16 + lq) * 80 + g * 16);
            osum[dt] = __builtin_amdgcn_mfma_f32_16x16x32_f16(av, bp.v, osum[dt], 0, 0, 0);
        }
    }

    const float inv = 1.0f / l_run;
    #pragma unroll
    for (int dt = 0; dt < 4; ++dt)
        #pragma unroll
        for (int j = 0; j < 4; ++j)
            Osm[wave][lq][dt * 16 + 4 * g + j] = osum[dt][j] * inv;
    __syncthreads();
    {
        float* ob = out + (((long)b * Ll + q0 + wave * 16) * Hh + h) * Dd;
        #pragma unroll
        for (int r = 0; r < 16; ++r)
            ob[(long)r * (Hh * Dd) + lane] = Osm[wave][r][lane];
    }
}

extern "C" void kernel_launch(void* const* d_in, const int* in_sizes, int n_in,
                              void* d_out, int out_size, void* d_ws, size_t ws_size,
                              hipStream_t stream) {
    const float* Q     = (const float*)d_in[0];
    const float* K     = (const float*)d_in[1];
    const float* V     = (const float*)d_in[2];
    const float* tau   = (const float*)d_in[3];
    const float* delta = (const float*)d_in[4];
    float* out = (float*)d_out;

    const size_t elems = (size_t)Bb * Hh * Ss * Ee;            // 4M per tensor
    const size_t need  = elems * 2 * 2 + (size_t)Bb * Ss * 4;  // K16 + VT16 + delta2

    if (ws_size >= need) {
        _Float16* K16    = (_Float16*)d_ws;
        _Float16* VT16   = K16 + elems;
        float*    delta2 = (float*)(VT16 + elems);
        hipLaunchKernelGGL(prepass_k, dim3(elems / 4 / 256), dim3(256), 0, stream,
                           K, K16, delta, delta2);
        hipLaunchKernelGGL(prepass_v, dim3(Ss / 64, Bb * Hh), dim3(256), 0, stream, V, VT16);
        hipLaunchKernelGGL(dsattn_fwd_v6, dim3(512), dim3(512), 65536, stream,
                           Q, K16, VT16, tau, delta2, out);
    } else {
        hipLaunchKernelGGL(dsattn_fwd, dim3(Ll / 64, Bb * Hh), dim3(256), 0, stream,
                           Q, K, V, tau, delta, out);
    }
}

// Round 15
// 89.831 us; speedup vs baseline: 1.0591x; 1.0591x over previous
//
#include <hip/hip_runtime.h>

// DSAttention forward, MI355X gfx950.
// B=2, L=S=2048, H=16, E=D=64. fp32 in/out, fp16 MFMA compute.
//
// Round 13 (v7): v6 + softmax cross-lane reduces taken off the steady-state
// critical path: per-lane defer-max vote (__all on local max, no DS) and
// lazy l-reduction (per-lane partial, combined once at epilogue). The only
// per-iteration DS ops left are the 8 independent pack shuffles per q-group.
// Carries: XCD-aware block decode, split-S 8-wave blocks, 2-phase staging.

#define Bb 2
#define Ll 2048
#define Ss 2048
#define Hh 16
#define Ee 64
#define Dd 64
#define KV 64

typedef _Float16 f16x8 __attribute__((ext_vector_type(8)));
typedef _Float16 f16x4 __attribute__((ext_vector_type(4)));
typedef __fp16 fp16x2 __attribute__((ext_vector_type(2)));
typedef float f32x4 __attribute__((ext_vector_type(4)));

union Pk2 { fp16x2 h; unsigned u; };
union PackU { unsigned u[4]; f16x8 v; };

#define GLDS(gp, lp) __builtin_amdgcn_global_load_lds( \
    (const __attribute__((address_space(1))) void*)(gp), \
    (__attribute__((address_space(3))) void*)(lp), 16, 0, 0)

// -------- pre-pass: K fp32 [B,S,H,E] -> fp16 [B,H,S,E]; delta2 = 0.125*delta --------
__global__ __launch_bounds__(256)
void prepass_k(const float* __restrict__ K, _Float16* __restrict__ K16,
               const float* __restrict__ delta, float* __restrict__ delta2)
{
    const unsigned v = blockIdx.x * 256 + threadIdx.x;   // float4 id, 1M total
    const unsigned e4 = v & 15;
    const unsigned h  = (v >> 4) & 15;
    const unsigned s  = (v >> 8) & (Ss - 1);
    const unsigned b  = v >> 19;
    const f32x4 src = ((const f32x4*)K)[v];
    f16x4 t;
    t[0] = (_Float16)src[0]; t[1] = (_Float16)src[1];
    t[2] = (_Float16)src[2]; t[3] = (_Float16)src[3];
    ((f16x4*)K16)[(((size_t)(b * Hh + h) * Ss + s) * 16) + e4] = t;
    if (v < (Bb * Ss) / 4) {
        f32x4 dd = ((const f32x4*)delta)[v];
        ((f32x4*)delta2)[v] = (f32x4){0.125f * dd[0], 0.125f * dd[1],
                                      0.125f * dd[2], 0.125f * dd[3]};
    }
}

// ------------- pre-pass: V fp32 [B,S,H,D] -> fp16 transposed [B,H,D,S] -------------
__global__ __launch_bounds__(256)
void prepass_v(const float* __restrict__ V, _Float16* __restrict__ VT16)
{
    __shared__ _Float16 TL[64][66];
    const int tid  = threadIdx.x;
    const int wave = tid >> 6;
    const int lane = tid & 63;
    const int bh = blockIdx.y;
    const int b  = bh >> 4;
    const int h  = bh & 15;
    const int s0 = blockIdx.x * 64;

    #pragma unroll
    for (int rr = 0; rr < 16; ++rr) {
        const int row = wave * 16 + rr;
        TL[row][lane] = (_Float16)V[((size_t)(b * Ss + s0 + row) * Hh + h) * Dd + lane];
    }
    __syncthreads();
    const int d  = tid >> 2;
    const int sq = (tid & 3) * 16;
    union { _Float16 h[16]; f16x8 v[2]; } tmp;
    #pragma unroll
    for (int i = 0; i < 16; ++i) tmp.h[i] = TL[sq + i][d];
    f16x8* dp = (f16x8*)(VT16 + ((size_t)(b * Hh + h) * Dd + d) * Ss + s0 + sq);
    dp[0] = tmp.v[0];
    dp[1] = tmp.v[1];
}

// ---------------------------- main kernel (v7) ----------------------------
__global__ __launch_bounds__(512)
void dsattn_fwd_v7(const float* __restrict__ Q, const _Float16* __restrict__ K16,
                   const _Float16* __restrict__ VT16, const float* __restrict__ tau,
                   const float* __restrict__ delta2, float* __restrict__ out)
{
    // dynamic LDS, 65536 B:
    //   half H at H*32768: buf c at +c*16384 (K tile 8KB, V tile at +8192)
    //   epilogue: Part [4][2][16][68] f32 at 0, then Osm [128][68] at 0
    extern __shared__ __align__(16) unsigned char smem[];

    const int tid  = threadIdx.x;
    const int wave = tid >> 6;        // 0..7
    const int half = wave >> 2;       // s-half
    const int wq   = wave & 3;        // q-quarter within block
    const int lane = tid & 63;
    const int lq   = lane & 15;
    const int g    = lane >> 4;
    const int tid_h = tid & 255;      // id within the half's staging group

    // XCD-aware decode: block i -> XCD i&7; XCD j owns bh {4j..4j+3}.
    const int bid = blockIdx.x;       // 0..511
    const int xcd = bid & 7;
    const int kk  = bid >> 3;         // 0..63
    const int bh  = xcd * 4 + (kk & 3);
    const int b   = bh >> 4;
    const int h   = bh & 15;
    const int q0  = (kk >> 2) * 128;  // q-block 0..15
    const int qw  = q0 + wq * 32;     // wave covers 32 q (2 groups of 16)

    const float alpha = 0.125f * tau[b];

    // Q fragments: aq[qg][es], lane holds Q[qw+qg*16+lq][es*32 + g*8 + j]
    f16x8 aq[2][2];
    #pragma unroll
    for (int qg = 0; qg < 2; ++qg) {
        const float* qp = Q + (((size_t)b * Ll + qw + qg * 16 + lq) * Hh + h) * Ee;
        #pragma unroll
        for (int es = 0; es < 2; ++es) {
            const float* p = qp + es * 32 + g * 8;
            f16x8 t;
            #pragma unroll
            for (int j = 0; j < 8; ++j) t[j] = (_Float16)p[j];
            aq[qg][es] = t;
        }
    }

    f32x4 osum[2][4];
    #pragma unroll
    for (int qg = 0; qg < 2; ++qg)
        #pragma unroll
        for (int i = 0; i < 4; ++i) osum[qg][i] = (f32x4){0.f, 0.f, 0.f, 0.f};
    float m_run[2] = {-1e30f, -1e30f};
    float l_run[2] = {0.0f, 0.0f};    // PER-LANE partial (lazy reduction)

    const unsigned char* kb  = (const unsigned char*)(K16 + (size_t)(b * Hh + h) * Ss * Ee);
    const unsigned char* vtb = (const unsigned char*)(VT16 + (size_t)(b * Hh + h) * Dd * Ss);
    const float* d2b = delta2 + (size_t)b * Ss;

    const int row0  = tid_h >> 3;                     // 0..31; issue 1 = +32
    const int slotS = (tid_h & 7) ^ (row0 & 7);
    unsigned char* stBase = smem + half * 32768;      // this half's staging region
    const int sBase = half * (Ss / 2);                // this half's s origin

    // ---- prologue: stage tile 0 into buf 0; load delta regs for tile 0 ----
    {
        unsigned char* kw = stBase + wq * 1024;
        unsigned char* vw = stBase + 8192 + wq * 1024;
        GLDS(kb + (size_t)(sBase + row0) * 128 + slotS * 16,        kw);
        GLDS(kb + (size_t)(sBase + row0 + 32) * 128 + slotS * 16,   kw + 4096);
        GLDS(vtb + (size_t)row0 * (Ss * 2) + sBase * 2 + slotS * 16,        vw);
        GLDS(vtb + (size_t)(row0 + 32) * (Ss * 2) + sBase * 2 + slotS * 16, vw + 4096);
    }
    f32x4 dcur[4], dnxt[4];
    #pragma unroll
    for (int t = 0; t < 4; ++t)
        dcur[t] = *(const f32x4*)(d2b + sBase + t * 16 + 4 * g);
    __syncthreads();   // buf0 ready (both halves)

    const int srcA = lq + 32 * (g & 1);
    const int srcB = srcA + 16;
    const bool gh = (g >> 1);

    int cur = 0;
    for (int it = 0; it < Ss / 2 / KV; ++it) {
        const int sb = sBase + it * KV;
        const int nb = (it + 1 < Ss / 2 / KV);
        // ---- stage next tile into buf^1 (in flight during compute) ----
        if (nb) {
            unsigned char* kw = stBase + (cur ^ 1) * 16384 + wq * 1024;
            unsigned char* vw = kw + 8192;
            const int sn = sb + KV;
            GLDS(kb + (size_t)(sn + row0) * 128 + slotS * 16,        kw);
            GLDS(kb + (size_t)(sn + row0 + 32) * 128 + slotS * 16,   kw + 4096);
            GLDS(vtb + (size_t)row0 * (Ss * 2) + sn * 2 + slotS * 16,        vw);
            GLDS(vtb + (size_t)(row0 + 32) * (Ss * 2) + sn * 2 + slotS * 16, vw + 4096);
        }
        {   // prefetch next delta regs
            const int sn = nb ? sb + KV : sb;
            #pragma unroll
            for (int t = 0; t < 4; ++t)
                dnxt[t] = *(const f32x4*)(d2b + sn + t * 16 + 4 * g);
        }

        const unsigned char* Ksm = stBase + cur * 16384;
        const unsigned char* Vsm = Ksm + 8192;

        // ---- QK^T for both q-groups, sharing each K fragment read ----
        f32x4 c4[2][4];
        #pragma unroll
        for (int qg = 0; qg < 2; ++qg)
            #pragma unroll
            for (int t = 0; t < 4; ++t) c4[qg][t] = (f32x4){0.f, 0.f, 0.f, 0.f};
        __builtin_amdgcn_s_setprio(1);
        #pragma unroll
        for (int t = 0; t < 4; ++t) {
            const int srow = t * 16 + lq;
            #pragma unroll
            for (int es = 0; es < 2; ++es) {
                const int slot = (es * 4 + g) ^ (srow & 7);
                f16x8 ak = *(const f16x8*)(Ksm + srow * 128 + slot * 16);
                c4[0][t] = __builtin_amdgcn_mfma_f32_16x16x32_f16(ak, aq[0][es], c4[0][t], 0, 0, 0);
                c4[1][t] = __builtin_amdgcn_mfma_f32_16x16x32_f16(ak, aq[1][es], c4[1][t], 0, 0, 0);
            }
        }
        __builtin_amdgcn_s_setprio(0);

        // ---- per q-group: softmax (lane-local fast path) + pack + PV B-frags ----
        PackU bp[2][2];
        #pragma unroll
        for (int qg = 0; qg < 2; ++qg) {
            float p[16];
            float tmax = -1e30f;
            #pragma unroll
            for (int t = 0; t < 4; ++t)
                #pragma unroll
                for (int j = 0; j < 4; ++j) {
                    float z = fmaf(alpha, c4[qg][t][j], dcur[t][j]);
                    p[t * 4 + j] = z;
                    tmax = fmaxf(tmax, z);
                }
            // per-lane vote: if every lane's LOCAL max is within m_run+8, the row
            // max is too -> keep m_run, no cross-lane reduce (common case).
            if (!__all(tmax <= m_run[qg] + 8.0f)) {
                float rmax = fmaxf(tmax, __shfl_xor(tmax, 16));
                rmax = fmaxf(rmax, __shfl_xor(rmax, 32));
                const float m_new = fmaxf(m_run[qg], rmax);
                const float corr  = __expf(m_run[qg] - m_new);
                l_run[qg] *= corr;
                #pragma unroll
                for (int dt = 0; dt < 4; ++dt)
                    #pragma unroll
                    for (int j = 0; j < 4; ++j)
                        osum[qg][dt][j] *= corr;
                m_run[qg] = m_new;
            }
            float psum = 0.f;
            #pragma unroll
            for (int i = 0; i < 16; ++i) { p[i] = __expf(p[i] - m_run[qg]); psum += p[i]; }
            l_run[qg] += psum;   // per-lane partial; cross-lane sum at epilogue

            unsigned pk[8];
            #pragma unroll
            for (int t = 0; t < 4; ++t) {
                Pk2 u0, u1;
                u0.h = __builtin_amdgcn_cvt_pkrtz(p[4 * t], p[4 * t + 1]);
                u1.h = __builtin_amdgcn_cvt_pkrtz(p[4 * t + 2], p[4 * t + 3]);
                pk[t * 2] = u0.u;
                pk[t * 2 + 1] = u1.u;
            }
            #pragma unroll
            for (int ks = 0; ks < 2; ++ks) {
                unsigned a0 = __shfl(pk[ks * 4 + 0], srcA), a1 = __shfl(pk[ks * 4 + 1], srcA);
                unsigned a2 = __shfl(pk[ks * 4 + 2], srcA), a3 = __shfl(pk[ks * 4 + 3], srcA);
                unsigned b0 = __shfl(pk[ks * 4 + 0], srcB), b1 = __shfl(pk[ks * 4 + 1], srcB);
                unsigned b2 = __shfl(pk[ks * 4 + 2], srcB), b3 = __shfl(pk[ks * 4 + 3], srcB);
                bp[qg][ks].u[0] = gh ? a2 : a0;
                bp[qg][ks].u[1] = gh ? a3 : a1;
                bp[qg][ks].u[2] = gh ? b2 : b0;
                bp[qg][ks].u[3] = gh ? b3 : b1;
            }
        }

        // ---- PV for both q-groups, sharing each V fragment read ----
        __builtin_amdgcn_s_setprio(1);
        #pragma unroll
        for (int ks = 0; ks < 2; ++ks)
            #pragma unroll
            for (int dt = 0; dt < 4; ++dt) {
                const int vrow = dt * 16 + lq;
                const int slot = (ks * 4 + g) ^ (vrow & 7);
                f16x8 av = *(const f16x8*)(Vsm + vrow * 128 + slot * 16);
                osum[0][dt] = __builtin_amdgcn_mfma_f32_16x16x32_f16(av, bp[0][ks].v, osum[0][dt], 0, 0, 0);
                osum[1][dt] = __builtin_amdgcn_mfma_f32_16x16x32_f16(av, bp[1][ks].v, osum[1][dt], 0, 0, 0);
            }
        __builtin_amdgcn_s_setprio(0);

        __syncthreads();   // next-tile GLDS drained; all waves done with buf[cur]
        cur ^= 1;
        #pragma unroll
        for (int t = 0; t < 4; ++t) dcur[t] = dnxt[t];
    }

    // ---- finalize per-lane l partials -> per-q totals (once) ----
    #pragma unroll
    for (int qg = 0; qg < 2; ++qg) {
        float l = l_run[qg];
        l += __shfl_xor(l, 16);
        l += __shfl_xor(l, 32);
        l_run[qg] = l;
    }

    // ---- epilogue: flash-combine the two s-halves, then coalesced store ----
    float (*Part)[2][16][68] = (float (*)[2][16][68])smem;   // [4][2][16][68]
    if (half == 1) {
        #pragma unroll
        for (int qg = 0; qg < 2; ++qg) {
            #pragma unroll
            for (int dt = 0; dt < 4; ++dt)
                *(f32x4*)&Part[wq][qg][lq][dt * 16 + 4 * g] = osum[qg][dt];
            if (g == 0) {
                Part[wq][qg][lq][64] = m_run[qg];
                Part[wq][qg][lq][65] = l_run[qg];
            }
        }
    }
    __syncthreads();
    if (half == 0) {
        #pragma unroll
        for (int qg = 0; qg < 2; ++qg) {
            const float m1 = Part[wq][qg][lq][64];
            const float l1 = Part[wq][qg][lq][65];
            const float m  = fmaxf(m_run[qg], m1);
            const float s0 = __expf(m_run[qg] - m);
            const float s1 = __expf(m1 - m);
            const float inv = 1.0f / (l_run[qg] * s0 + l1 * s1);
            #pragma unroll
            for (int dt = 0; dt < 4; ++dt) {
                f32x4 p1 = *(const f32x4*)&Part[wq][qg][lq][dt * 16 + 4 * g];
                #pragma unroll
                for (int j = 0; j < 4; ++j)
                    osum[qg][dt][j] = (osum[qg][dt][j] * s0 + p1[j] * s1) * inv;
            }
        }
    }
    __syncthreads();   // all Part reads done; smem reusable
    float (*Osm)[68] = (float (*)[68])smem;                  // [128][68]
    if (half == 0) {
        #pragma unroll
        for (int qg = 0; qg < 2; ++qg)
            #pragma unroll
            for (int dt = 0; dt < 4; ++dt)
                *(f32x4*)&Osm[wq * 32 + qg * 16 + lq][dt * 16 + 4 * g] = osum[qg][dt];
    }
    __syncthreads();
    {
        float* ob = out + (((size_t)b * Ll + q0) * Hh + h) * Dd;
        #pragma unroll
        for (int i = 0; i < 16; ++i) {
            const int r = wave * 16 + i;
            ob[(size_t)r * (Hh * Dd) + lane] = Osm[r][lane];
        }
    }
}

// ---------------------------- fallback (v1, verified r5) ----------------------------
__global__ __launch_bounds__(256)
void dsattn_fwd(const float* __restrict__ Q, const float* __restrict__ K,
                const float* __restrict__ V, const float* __restrict__ tau,
                const float* __restrict__ delta, float* __restrict__ out)
{
    __shared__ __align__(16) unsigned char Ksm[32 * 128];
    __shared__ __align__(16) unsigned char VTsm[64 * 80];
    __shared__ float dsm[32];
    __shared__ float Osm[4][16][68];

    const int tid  = threadIdx.x;
    const int wave = tid >> 6;
    const int lane = tid & 63;
    const int lq   = lane & 15;
    const int g    = lane >> 4;

    const int bh = blockIdx.y;
    const int b  = bh >> 4;
    const int h  = bh & 15;
    const int q0 = blockIdx.x * 64;

    const float alpha = 0.125f * tau[b];

    f16x8 aq[2];
    {
        const float* qp = Q + (((long)b * Ll + q0 + wave * 16 + lq) * Hh + h) * Ee;
        #pragma unroll
        for (int es = 0; es < 2; ++es) {
            const float* p = qp + es * 32 + g * 8;
            f16x8 t;
            #pragma unroll
            for (int j = 0; j < 8; ++j) t[j] = (_Float16)p[j];
            aq[es] = t;
        }
    }

    f32x4 osum[4];
    #pragma unroll
    for (int i = 0; i < 4; ++i) osum[i] = (f32x4){0.f, 0.f, 0.f, 0.f};
    float m_run = -1e30f, l_run = 0.0f;

    const float* kb = K + ((long)b * Ss * Hh + h) * Ee;
    const float* vb = V + ((long)b * Ss * Hh + h) * Dd;
    const float* db = delta + (long)b * Ss;

    const int kr    = tid >> 3;
    const int kc    = (tid & 7) * 8;
    const int kslot = (((tid & 7) ^ (kr & 7)) * 16);
    const int vd    = tid & 63;
    const int vsh   = tid >> 6;

    for (int sb = 0; sb < Ss; sb += 32) {
        __syncthreads();
        {
            const float* src = kb + (long)(sb + kr) * (Hh * Ee) + kc;
            f16x8 t;
            #pragma unroll
            for (int j = 0; j < 8; ++j) t[j] = (_Float16)src[j];
            *(f16x8*)(Ksm + kr * 128 + kslot) = t;
        }
        {
            const float* src = vb + (long)(sb + vsh * 8) * (Hh * Dd) + vd;
            f16x8 t;
            #pragma unroll
            for (int j = 0; j < 8; ++j) t[j] = (_Float16)src[j * (Hh * Dd)];
            *(f16x8*)(VTsm + vd * 80 + vsh * 16) = t;
        }
        if (tid < 32) dsm[tid] = 0.125f * db[sb + tid];
        __syncthreads();

        float p[8];
        float tmax = -1e30f;
        #pragma unroll
        for (int t = 0; t < 2; ++t) {
            f32x4 c = (f32x4){0.f, 0.f, 0.f, 0.f};
            #pragma unroll
            for (int es = 0; es < 2; ++es) {
                const int srow = t * 16 + lq;
                const int slot = ((es * 4 + g) ^ (srow & 7)) * 16;
                f16x8 ak = *(const f16x8*)(Ksm + srow * 128 + slot);
                c = __builtin_amdgcn_mfma_f32_16x16x32_f16(ak, aq[es], c, 0, 0, 0);
            }
            #pragma unroll
            for (int j = 0; j < 4; ++j) {
                float z = alpha * c[j] + dsm[t * 16 + 4 * g + j];
                p[t * 4 + j] = z;
                tmax = fmaxf(tmax, z);
            }
        }
        tmax = fmaxf(tmax, __shfl_xor(tmax, 16));
        tmax = fmaxf(tmax, __shfl_xor(tmax, 32));
        const float m_new = fmaxf(m_run, tmax);
        const float corr  = __expf(m_run - m_new);
        float psum = 0.f;
        #pragma unroll
        for (int i = 0; i < 8; ++i) { p[i] = __expf(p[i] - m_new); psum += p[i]; }
        psum += __shfl_xor(psum, 16);
        psum += __shfl_xor(psum, 32);
        l_run = l_run * corr + psum;
        m_run = m_new;
        #pragma unroll
        for (int dt = 0; dt < 4; ++dt)
            #pragma unroll
            for (int j = 0; j < 4; ++j)
                osum[dt][j] *= corr;

        Pk2 u00, u01, u10, u11;
        u00.h = __builtin_amdgcn_cvt_pkrtz(p[0], p[1]);
        u01.h = __builtin_amdgcn_cvt_pkrtz(p[2], p[3]);
        u10.h = __builtin_amdgcn_cvt_pkrtz(p[4], p[5]);
        u11.h = __builtin_amdgcn_cvt_pkrtz(p[6], p[7]);
        const int srcA = lq + 32 * (g & 1);
        const int srcB = srcA + 16;
        unsigned a00 = __shfl(u00.u, srcA), a01 = __shfl(u01.u, srcA);
        unsigned a10 = __shfl(u10.u, srcA), a11 = __shfl(u11.u, srcA);
        unsigned b00 = __shfl(u00.u, srcB), b01 = __shfl(u01.u, srcB);
        unsigned b10 = __shfl(u10.u, srcB), b11 = __shfl(u11.u, srcB);
        const bool hi = (g >= 2);
        PackU bp;
        bp.u[0] = hi ? a10 : a00;
        bp.u[1] = hi ? a11 : a01;
        bp.u[2] = hi ? b10 : b00;
        bp.u[3] = hi ? b11 : b01;

        #pragma unroll
        for (int dt = 0; dt < 4; ++dt) {
            f16x8 av = *(const f16x8*)(VTsm + (dt * 16 + lq) * 80 + g * 16);
            osum[dt] = __builtin_amdgcn_mfma_f32_16x16x32_f16(av, bp.v, osum[dt], 0, 0, 0);
        }
    }

    const float inv = 1.0f / l_run;
    #pragma unroll
    for (int dt = 0; dt < 4; ++dt)
        #pragma unroll
        for (int j = 0; j < 4; ++j)
            Osm[wave][lq][dt * 16 + 4 * g + j] = osum[dt][j] * inv;
    __syncthreads();
    {
        float* ob = out + (((long)b * Ll + q0 + wave * 16) * Hh + h) * Dd;
        #pragma unroll
        for (int r = 0; r < 16; ++r)
            ob[(long)r * (Hh * Dd) + lane] = Osm[wave][r][lane];
    }
}

extern "C" void kernel_launch(void* const* d_in, const int* in_sizes, int n_in,
                              void* d_out, int out_size, void* d_ws, size_t ws_size,
                              hipStream_t stream) {
    const float* Q     = (const float*)d_in[0];
    const float* K     = (const float*)d_in[1];
    const float* V     = (const float*)d_in[2];
    const float* tau   = (const float*)d_in[3];
    const float* delta = (const float*)d_in[4];
    float* out = (float*)d_out;

    const size_t elems = (size_t)Bb * Hh * Ss * Ee;            // 4M per tensor
    const size_t need  = elems * 2 * 2 + (size_t)Bb * Ss * 4;  // K16 + VT16 + delta2

    if (ws_size >= need) {
        _Float16* K16    = (_Float16*)d_ws;
        _Float16* VT16   = K16 + elems;
        float*    delta2 = (float*)(VT16 + elems);
        hipLaunchKernelGGL(prepass_k, dim3(elems / 4 / 256), dim3(256), 0, stream,
                           K, K16, delta, delta2);
        hipLaunchKernelGGL(prepass_v, dim3(Ss / 64, Bb * Hh), dim3(256), 0, stream, V, VT16);
        hipLaunchKernelGGL(dsattn_fwd_v7, dim3(512), dim3(512), 65536, stream,
                           Q, K16, VT16, tau, delta2, out);
    } else {
        hipLaunchKernelGGL(dsattn_fwd, dim3(Ll / 64, Bb * Hh), dim3(256), 0, stream,
                           Q, K, V, tau, delta, out);
    }
}

// Round 16
// 86.959 us; speedup vs baseline: 1.0940x; 1.0330x over previous
//
#include <hip/hip_runtime.h>

// DSAttention forward, MI355X gfx950.
// B=2, L=S=2048, H=16, E=D=64. fp32 in/out, fp16 MFMA compute.
//
// Round 15 (v8): 1-deep software pipeline: body t = {stage K[t+2],V[t+1];
// QK^T(t+1) MFMA -> cnext; softmax(t) on cprev (VALU, overlaps in-flight MFMA);
// pack; PV(t); barrier}. Unroll-2 alternates (cA,dA)/(cB,dB) register sets.
// Softmax in exp2 domain (log2e folded into alpha/delta2) -> 1-inst exp.
// Carries: XCD decode, split-S 8-wave blocks, per-lane defer vote, lazy l.

#define Bb 2
#define Ll 2048
#define Ss 2048
#define Hh 16
#define Ee 64
#define Dd 64
#define KV 64
#define NT 16   // (Ss/2)/KV per half

typedef _Float16 f16x8 __attribute__((ext_vector_type(8)));
typedef _Float16 f16x4 __attribute__((ext_vector_type(4)));
typedef __fp16 fp16x2 __attribute__((ext_vector_type(2)));
typedef float f32x4 __attribute__((ext_vector_type(4)));

union Pk2 { fp16x2 h; unsigned u; };
union PackU { unsigned u[4]; f16x8 v; };

#define GLDS(gp, lp) __builtin_amdgcn_global_load_lds( \
    (const __attribute__((address_space(1))) void*)(gp), \
    (__attribute__((address_space(3))) void*)(lp), 16, 0, 0)

#if __has_builtin(__builtin_amdgcn_exp2f)
#define EXP2(x) __builtin_amdgcn_exp2f(x)
#else
#define EXP2(x) exp2f(x)
#endif

#define LOG2E 1.4426950408889634f

// ---- pre-pass: K fp32 [B,S,H,E] -> fp16 [B,H,S,E]; delta2 = 0.125*log2e*delta ----
__global__ __launch_bounds__(256)
void prepass_k(const float* __restrict__ K, _Float16* __restrict__ K16,
               const float* __restrict__ delta, float* __restrict__ delta2)
{
    const unsigned v = blockIdx.x * 256 + threadIdx.x;   // float4 id, 1M total
    const unsigned e4 = v & 15;
    const unsigned h  = (v >> 4) & 15;
    const unsigned s  = (v >> 8) & (Ss - 1);
    const unsigned b  = v >> 19;
    const f32x4 src = ((const f32x4*)K)[v];
    f16x4 t;
    t[0] = (_Float16)src[0]; t[1] = (_Float16)src[1];
    t[2] = (_Float16)src[2]; t[3] = (_Float16)src[3];
    ((f16x4*)K16)[(((size_t)(b * Hh + h) * Ss + s) * 16) + e4] = t;
    if (v < (Bb * Ss) / 4) {
        const float sc = 0.125f * LOG2E;
        f32x4 dd = ((const f32x4*)delta)[v];
        ((f32x4*)delta2)[v] = (f32x4){sc * dd[0], sc * dd[1], sc * dd[2], sc * dd[3]};
    }
}

// ------------- pre-pass: V fp32 [B,S,H,D] -> fp16 transposed [B,H,D,S] -------------
__global__ __launch_bounds__(256)
void prepass_v(const float* __restrict__ V, _Float16* __restrict__ VT16)
{
    __shared__ _Float16 TL[64][66];
    const int tid  = threadIdx.x;
    const int wave = tid >> 6;
    const int lane = tid & 63;
    const int bh = blockIdx.y;
    const int b  = bh >> 4;
    const int h  = bh & 15;
    const int s0 = blockIdx.x * 64;

    #pragma unroll
    for (int rr = 0; rr < 16; ++rr) {
        const int row = wave * 16 + rr;
        TL[row][lane] = (_Float16)V[((size_t)(b * Ss + s0 + row) * Hh + h) * Dd + lane];
    }
    __syncthreads();
    const int d  = tid >> 2;
    const int sq = (tid & 3) * 16;
    union { _Float16 h[16]; f16x8 v[2]; } tmp;
    #pragma unroll
    for (int i = 0; i < 16; ++i) tmp.h[i] = TL[sq + i][d];
    f16x8* dp = (f16x8*)(VT16 + ((size_t)(b * Hh + h) * Dd + d) * Ss + s0 + sq);
    dp[0] = tmp.v[0];
    dp[1] = tmp.v[1];
}

// ---------------------------- main kernel (v8) ----------------------------
// LDS per half (32768 B at stBase): Kbuf c @ c*8192, Vbuf c @ 16384 + c*8192.

#define PBODY(T, CP, CN, DP, DN)                                                     \
{                                                                                    \
    const int sb_ = sBase + (T) * KV;                                                \
    if ((T) + 2 < NT) {                                                              \
        unsigned char* kw = stBase + ((T) & 1) * 8192 + wq * 1024;                   \
        GLDS(kb + (size_t)(sb_ + 2 * KV + row0) * 128 + slotS * 16, kw);             \
        GLDS(kb + (size_t)(sb_ + 2 * KV + row0 + 32) * 128 + slotS * 16, kw + 4096); \
    }                                                                                \
    if ((T) + 1 < NT) {                                                              \
        unsigned char* vw = stBase + 16384 + (((T) + 1) & 1) * 8192 + wq * 1024;     \
        GLDS(vtb + (size_t)row0 * (Ss * 2) + (sb_ + KV) * 2 + slotS * 16, vw);       \
        GLDS(vtb + (size_t)(row0 + 32) * (Ss * 2) + (sb_ + KV) * 2 + slotS * 16, vw + 4096); \
        _Pragma("unroll")                                                            \
        for (int q4 = 0; q4 < 4; ++q4)                                               \
            DN[q4] = *(const f32x4*)(d2b + sb_ + KV + q4 * 16 + 4 * g);              \
        const unsigned char* Ksm = stBase + (((T) + 1) & 1) * 8192;                  \
        _Pragma("unroll")                                                            \
        for (int qg = 0; qg < 2; ++qg)                                               \
            _Pragma("unroll")                                                        \
            for (int t4 = 0; t4 < 4; ++t4)                                           \
                CN[qg][t4] = (f32x4){0.f, 0.f, 0.f, 0.f};                            \
        __builtin_amdgcn_s_setprio(1);                                               \
        _Pragma("unroll")                                                            \
        for (int t4 = 0; t4 < 4; ++t4) {                                             \
            const int srow = t4 * 16 + lq;                                           \
            _Pragma("unroll")                                                        \
            for (int es = 0; es < 2; ++es) {                                         \
                const int slot = (es * 4 + g) ^ (srow & 7);                          \
                f16x8 ak = *(const f16x8*)(Ksm + srow * 128 + slot * 16);            \
                CN[0][t4] = __builtin_amdgcn_mfma_f32_16x16x32_f16(ak, aq[0][es], CN[0][t4], 0, 0, 0); \
                CN[1][t4] = __builtin_amdgcn_mfma_f32_16x16x32_f16(ak, aq[1][es], CN[1][t4], 0, 0, 0); \
            }                                                                        \
        }                                                                            \
        __builtin_amdgcn_s_setprio(0);                                               \
    }                                                                                \
    PackU bp[2][2];                                                                  \
    _Pragma("unroll")                                                                \
    for (int qg = 0; qg < 2; ++qg) {                                                 \
        float p[16];                                                                 \
        float tmax = -1e30f;                                                         \
        _Pragma("unroll")                                                            \
        for (int t4 = 0; t4 < 4; ++t4)                                               \
            _Pragma("unroll")                                                        \
            for (int j = 0; j < 4; ++j) {                                            \
                float z = fmaf(alpha2, CP[qg][t4][j], DP[t4][j]);                    \
                p[t4 * 4 + j] = z;                                                   \
                tmax = fmaxf(tmax, z);                                               \
            }                                                                        \
        if (!__all(tmax <= m_run[qg] + 11.5416f)) {                                  \
            float rmax = fmaxf(tmax, __shfl_xor(tmax, 16));                          \
            rmax = fmaxf(rmax, __shfl_xor(rmax, 32));                                \
            const float m_new = fmaxf(m_run[qg], rmax);                              \
            const float corr = EXP2(m_run[qg] - m_new);                              \
            l_run[qg] *= corr;                                                       \
            _Pragma("unroll")                                                        \
            for (int dt = 0; dt < 4; ++dt)                                           \
                _Pragma("unroll")                                                    \
                for (int j = 0; j < 4; ++j) osum[qg][dt][j] *= corr;                 \
            m_run[qg] = m_new;                                                       \
        }                                                                            \
        float psum = 0.f;                                                            \
        _Pragma("unroll")                                                            \
        for (int i = 0; i < 16; ++i) { p[i] = EXP2(p[i] - m_run[qg]); psum += p[i]; } \
        l_run[qg] += psum;                                                           \
        unsigned pk[8];                                                              \
        _Pragma("unroll")                                                            \
        for (int t4 = 0; t4 < 4; ++t4) {                                             \
            Pk2 u0, u1;                                                              \
            u0.h = __builtin_amdgcn_cvt_pkrtz(p[4 * t4], p[4 * t4 + 1]);             \
            u1.h = __builtin_amdgcn_cvt_pkrtz(p[4 * t4 + 2], p[4 * t4 + 3]);         \
            pk[t4 * 2] = u0.u;                                                       \
            pk[t4 * 2 + 1] = u1.u;                                                   \
        }                                                                            \
        _Pragma("unroll")                                                            \
        for (int ks = 0; ks < 2; ++ks) {                                             \
            unsigned a0 = __shfl(pk[ks * 4 + 0], srcA), a1 = __shfl(pk[ks * 4 + 1], srcA); \
            unsigned a2 = __shfl(pk[ks * 4 + 2], srcA), a3 = __shfl(pk[ks * 4 + 3], srcA); \
            unsigned b0 = __shfl(pk[ks * 4 + 0], srcB), b1 = __shfl(pk[ks * 4 + 1], srcB); \
            unsigned b2 = __shfl(pk[ks * 4 + 2], srcB), b3 = __shfl(pk[ks * 4 + 3], srcB); \
            bp[qg][ks].u[0] = gh ? a2 : a0;                                          \
            bp[qg][ks].u[1] = gh ? a3 : a1;                                          \
            bp[qg][ks].u[2] = gh ? b2 : b0;                                          \
            bp[qg][ks].u[3] = gh ? b3 : b1;                                          \
        }                                                                            \
    }                                                                                \
    {                                                                                \
        const unsigned char* Vsm = stBase + 16384 + ((T) & 1) * 8192;                \
        __builtin_amdgcn_s_setprio(1);                                               \
        _Pragma("unroll")                                                            \
        for (int ks = 0; ks < 2; ++ks)                                               \
            _Pragma("unroll")                                                        \
            for (int dt = 0; dt < 4; ++dt) {                                         \
                const int vrow = dt * 16 + lq;                                       \
                const int slot = (ks * 4 + g) ^ (vrow & 7);                          \
                f16x8 av = *(const f16x8*)(Vsm + vrow * 128 + slot * 16);            \
                osum[0][dt] = __builtin_amdgcn_mfma_f32_16x16x32_f16(av, bp[0][ks].v, osum[0][dt], 0, 0, 0); \
                osum[1][dt] = __builtin_amdgcn_mfma_f32_16x16x32_f16(av, bp[1][ks].v, osum[1][dt], 0, 0, 0); \
            }                                                                        \
        __builtin_amdgcn_s_setprio(0);                                               \
    }                                                                                \
    __syncthreads();                                                                 \
}

__global__ __launch_bounds__(512)
void dsattn_fwd_v8(const float* __restrict__ Q, const _Float16* __restrict__ K16,
                   const _Float16* __restrict__ VT16, const float* __restrict__ tau,
                   const float* __restrict__ delta2, float* __restrict__ out)
{
    extern __shared__ __align__(16) unsigned char smem[];

    const int tid  = threadIdx.x;
    const int wave = tid >> 6;        // 0..7
    const int half = wave >> 2;       // s-half
    const int wq   = wave & 3;        // q-quarter within block
    const int lane = tid & 63;
    const int lq   = lane & 15;
    const int g    = lane >> 4;
    const int tid_h = tid & 255;

    // XCD-aware decode: block i -> XCD i&7; XCD j owns bh {4j..4j+3}.
    const int bid = blockIdx.x;
    const int xcd = bid & 7;
    const int kk  = bid >> 3;
    const int bh  = xcd * 4 + (kk & 3);
    const int b   = bh >> 4;
    const int h   = bh & 15;
    const int q0  = (kk >> 2) * 128;
    const int qw  = q0 + wq * 32;

    const float alpha2 = 0.125f * LOG2E * tau[b];

    // Q fragments
    f16x8 aq[2][2];
    #pragma unroll
    for (int qg = 0; qg < 2; ++qg) {
        const float* qp = Q + (((size_t)b * Ll + qw + qg * 16 + lq) * Hh + h) * Ee;
        #pragma unroll
        for (int es = 0; es < 2; ++es) {
            const float* p = qp + es * 32 + g * 8;
            f16x8 t;
            #pragma unroll
            for (int j = 0; j < 8; ++j) t[j] = (_Float16)p[j];
            aq[qg][es] = t;
        }
    }

    f32x4 osum[2][4];
    #pragma unroll
    for (int qg = 0; qg < 2; ++qg)
        #pragma unroll
        for (int i = 0; i < 4; ++i) osum[qg][i] = (f32x4){0.f, 0.f, 0.f, 0.f};
    float m_run[2] = {-1e30f, -1e30f};
    float l_run[2] = {0.0f, 0.0f};    // per-lane partial

    const unsigned char* kb  = (const unsigned char*)(K16 + (size_t)(b * Hh + h) * Ss * Ee);
    const unsigned char* vtb = (const unsigned char*)(VT16 + (size_t)(b * Hh + h) * Dd * Ss);
    const float* d2b = delta2 + (size_t)b * Ss;

    const int row0  = tid_h >> 3;
    const int slotS = (tid_h & 7) ^ (row0 & 7);
    unsigned char* stBase = smem + half * 32768;
    const int sBase = half * (Ss / 2);

    const int srcA = lq + 32 * (g & 1);
    const int srcB = srcA + 16;
    const bool gh = (g >> 1);

    // ---- prologue: stage K[0]->Kbuf0, V[0]->Vbuf0, K[1]->Kbuf1; d[0]; QK(0) ----
    {
        unsigned char* kw0 = stBase + wq * 1024;
        GLDS(kb + (size_t)(sBase + row0) * 128 + slotS * 16, kw0);
        GLDS(kb + (size_t)(sBase + row0 + 32) * 128 + slotS * 16, kw0 + 4096);
        unsigned char* vw0 = stBase + 16384 + wq * 1024;
        GLDS(vtb + (size_t)row0 * (Ss * 2) + sBase * 2 + slotS * 16, vw0);
        GLDS(vtb + (size_t)(row0 + 32) * (Ss * 2) + sBase * 2 + slotS * 16, vw0 + 4096);
        unsigned char* kw1 = stBase + 8192 + wq * 1024;
        GLDS(kb + (size_t)(sBase + KV + row0) * 128 + slotS * 16, kw1);
        GLDS(kb + (size_t)(sBase + KV + row0 + 32) * 128 + slotS * 16, kw1 + 4096);
    }
    f32x4 dA[4], dB[4];
    #pragma unroll
    for (int q4 = 0; q4 < 4; ++q4)
        dA[q4] = *(const f32x4*)(d2b + sBase + q4 * 16 + 4 * g);
    __syncthreads();   // buf0/buf1 K, buf0 V ready

    f32x4 cA[2][4], cB[2][4];
    #pragma unroll
    for (int qg = 0; qg < 2; ++qg)
        #pragma unroll
        for (int t4 = 0; t4 < 4; ++t4) cA[qg][t4] = (f32x4){0.f, 0.f, 0.f, 0.f};
    {
        const unsigned char* Ksm = stBase;   // Kbuf0
        #pragma unroll
        for (int t4 = 0; t4 < 4; ++t4) {
            const int srow = t4 * 16 + lq;
            #pragma unroll
            for (int es = 0; es < 2; ++es) {
                const int slot = (es * 4 + g) ^ (srow & 7);
                f16x8 ak = *(const f16x8*)(Ksm + srow * 128 + slot * 16);
                cA[0][t4] = __builtin_amdgcn_mfma_f32_16x16x32_f16(ak, aq[0][es], cA[0][t4], 0, 0, 0);
                cA[1][t4] = __builtin_amdgcn_mfma_f32_16x16x32_f16(ak, aq[1][es], cA[1][t4], 0, 0, 0);
            }
        }
    }
    __syncthreads();   // all waves done reading Kbuf0 before BODY(0) stages K[2] into it

    for (int t = 0; t < NT; t += 2) {
        PBODY(t,     cA, cB, dA, dB);
        PBODY(t + 1, cB, cA, dB, dA);
    }

    // ---- finalize per-lane l partials -> per-q totals ----
    #pragma unroll
    for (int qg = 0; qg < 2; ++qg) {
        float l = l_run[qg];
        l += __shfl_xor(l, 16);
        l += __shfl_xor(l, 32);
        l_run[qg] = l;
    }

    // ---- epilogue: flash-combine the two s-halves, then coalesced store ----
    float (*Part)[2][16][68] = (float (*)[2][16][68])smem;
    if (half == 1) {
        #pragma unroll
        for (int qg = 0; qg < 2; ++qg) {
            #pragma unroll
            for (int dt = 0; dt < 4; ++dt)
                *(f32x4*)&Part[wq][qg][lq][dt * 16 + 4 * g] = osum[qg][dt];
            if (g == 0) {
                Part[wq][qg][lq][64] = m_run[qg];
                Part[wq][qg][lq][65] = l_run[qg];
            }
        }
    }
    __syncthreads();
    if (half == 0) {
        #pragma unroll
        for (int qg = 0; qg < 2; ++qg) {
            const float m1 = Part[wq][qg][lq][64];
            const float l1 = Part[wq][qg][lq][65];
            const float m  = fmaxf(m_run[qg], m1);
            const float s0 = EXP2(m_run[qg] - m);
            const float s1 = EXP2(m1 - m);
            const float inv = 1.0f / (l_run[qg] * s0 + l1 * s1);
            #pragma unroll
            for (int dt = 0; dt < 4; ++dt) {
                f32x4 p1 = *(const f32x4*)&Part[wq][qg][lq][dt * 16 + 4 * g];
                #pragma unroll
                for (int j = 0; j < 4; ++j)
                    osum[qg][dt][j] = (osum[qg][dt][j] * s0 + p1[j] * s1) * inv;
            }
        }
    }
    __syncthreads();
    float (*Osm)[68] = (float (*)[68])smem;
    if (half == 0) {
        #pragma unroll
        for (int qg = 0; qg < 2; ++qg)
            #pragma unroll
            for (int dt = 0; dt < 4; ++dt)
                *(f32x4*)&Osm[wq * 32 + qg * 16 + lq][dt * 16 + 4 * g] = osum[qg][dt];
    }
    __syncthreads();
    {
        float* ob = out + (((size_t)b * Ll + q0) * Hh + h) * Dd;
        #pragma unroll
        for (int i = 0; i < 16; ++i) {
            const int r = wave * 16 + i;
            ob[(size_t)r * (Hh * Dd) + lane] = Osm[r][lane];
        }
    }
}

// ---------------------------- fallback (v1, verified r5) ----------------------------
__global__ __launch_bounds__(256)
void dsattn_fwd(const float* __restrict__ Q, const float* __restrict__ K,
                const float* __restrict__ V, const float* __restrict__ tau,
                const float* __restrict__ delta, float* __restrict__ out)
{
    __shared__ __align__(16) unsigned char Ksm[32 * 128];
    __shared__ __align__(16) unsigned char VTsm[64 * 80];
    __shared__ float dsm[32];
    __shared__ float Osm[4][16][68];

    const int tid  = threadIdx.x;
    const int wave = tid >> 6;
    const int lane = tid & 63;
    const int lq   = lane & 15;
    const int g    = lane >> 4;

    const int bh = blockIdx.y;
    const int b  = bh >> 4;
    const int h  = bh & 15;
    const int q0 = blockIdx.x * 64;

    const float alpha = 0.125f * tau[b];

    f16x8 aq[2];
    {
        const float* qp = Q + (((long)b * Ll + q0 + wave * 16 + lq) * Hh + h) * Ee;
        #pragma unroll
        for (int es = 0; es < 2; ++es) {
            const float* p = qp + es * 32 + g * 8;
            f16x8 t;
            #pragma unroll
            for (int j = 0; j < 8; ++j) t[j] = (_Float16)p[j];
            aq[es] = t;
        }
    }

    f32x4 osum[4];
    #pragma unroll
    for (int i = 0; i < 4; ++i) osum[i] = (f32x4){0.f, 0.f, 0.f, 0.f};
    float m_run = -1e30f, l_run = 0.0f;

    const float* kb = K + ((long)b * Ss * Hh + h) * Ee;
    const float* vb = V + ((long)b * Ss * Hh + h) * Dd;
    const float* db = delta + (long)b * Ss;

    const int kr    = tid >> 3;
    const int kc    = (tid & 7) * 8;
    const int kslot = (((tid & 7) ^ (kr & 7)) * 16);
    const int vd    = tid & 63;
    const int vsh   = tid >> 6;

    for (int sb = 0; sb < Ss; sb += 32) {
        __syncthreads();
        {
            const float* src = kb + (long)(sb + kr) * (Hh * Ee) + kc;
            f16x8 t;
            #pragma unroll
            for (int j = 0; j < 8; ++j) t[j] = (_Float16)src[j];
            *(f16x8*)(Ksm + kr * 128 + kslot) = t;
        }
        {
            const float* src = vb + (long)(sb + vsh * 8) * (Hh * Dd) + vd;
            f16x8 t;
            #pragma unroll
            for (int j = 0; j < 8; ++j) t[j] = (_Float16)src[j * (Hh * Dd)];
            *(f16x8*)(VTsm + vd * 80 + vsh * 16) = t;
        }
        if (tid < 32) dsm[tid] = 0.125f * db[sb + tid];
        __syncthreads();

        float p[8];
        float tmax = -1e30f;
        #pragma unroll
        for (int t = 0; t < 2; ++t) {
            f32x4 c = (f32x4){0.f, 0.f, 0.f, 0.f};
            #pragma unroll
            for (int es = 0; es < 2; ++es) {
                const int srow = t * 16 + lq;
                const int slot = ((es * 4 + g) ^ (srow & 7)) * 16;
                f16x8 ak = *(const f16x8*)(Ksm + srow * 128 + slot);
                c = __builtin_amdgcn_mfma_f32_16x16x32_f16(ak, aq[es], c, 0, 0, 0);
            }
            #pragma unroll
            for (int j = 0; j < 4; ++j) {
                float z = alpha * c[j] + dsm[t * 16 + 4 * g + j];
                p[t * 4 + j] = z;
                tmax = fmaxf(tmax, z);
            }
        }
        tmax = fmaxf(tmax, __shfl_xor(tmax, 16));
        tmax = fmaxf(tmax, __shfl_xor(tmax, 32));
        const float m_new = fmaxf(m_run, tmax);
        const float corr  = __expf(m_run - m_new);
        float psum = 0.f;
        #pragma unroll
        for (int i = 0; i < 8; ++i) { p[i] = __expf(p[i] - m_new); psum += p[i]; }
        psum += __shfl_xor(psum, 16);
        psum += __shfl_xor(psum, 32);
        l_run = l_run * corr + psum;
        m_run = m_new;
        #pragma unroll
        for (int dt = 0; dt < 4; ++dt)
            #pragma unroll
            for (int j = 0; j < 4; ++j)
                osum[dt][j] *= corr;

        Pk2 u00, u01, u10, u11;
        u00.h = __builtin_amdgcn_cvt_pkrtz(p[0], p[1]);
        u01.h = __builtin_amdgcn_cvt_pkrtz(p[2], p[3]);
        u10.h = __builtin_amdgcn_cvt_pkrtz(p[4], p[5]);
        u11.h = __builtin_amdgcn_cvt_pkrtz(p[6], p[7]);
        const int srcA = lq + 32 * (g & 1);
        const int srcB = srcA + 16;
        unsigned a00 = __shfl(u00.u, srcA), a01 = __shfl(u01.u, srcA);
        unsigned a10 = __shfl(u10.u, srcA), a11 = __shfl(u11.u, srcA);
        unsigned b00 = __shfl(u00.u, srcB), b01 = __shfl(u01.u, srcB);
        unsigned b10 = __shfl(u10.u, srcB), b11 = __shfl(u11.u, srcB);
        const bool hi = (g >= 2);
        PackU bp;
        bp.u[0] = hi ? a10 : a00;
        bp.u[1] = hi ? a11 : a01;
        bp.u[2] = hi ? b10 : b00;
        bp.u[3] = hi ? b11 : b01;

        #pragma unroll
        for (int dt = 0; dt < 4; ++dt) {
            f16x8 av = *(const f16x8*)(VTsm + (dt * 16 + lq) * 80 + g * 16);
            osum[dt] = __builtin_amdgcn_mfma_f32_16x16x32_f16(av, bp.v, osum[dt], 0, 0, 0);
        }
    }

    const float inv = 1.0f / l_run;
    #pragma unroll
    for (int dt = 0; dt < 4; ++dt)
        #pragma unroll
        for (int j = 0; j < 4; ++j)
            Osm[wave][lq][dt * 16 + 4 * g + j] = osum[dt][j] * inv;
    __syncthreads();
    {
        float* ob = out + (((long)b * Ll + q0 + wave * 16) * Hh + h) * Dd;
        #pragma unroll
        for (int r = 0; r < 16; ++r)
            ob[(long)r * (Hh * Dd) + lane] = Osm[wave][r][lane];
    }
}

extern "C" void kernel_launch(void* const* d_in, const int* in_sizes, int n_in,
                              void* d_out, int out_size, void* d_ws, size_t ws_size,
                              hipStream_t stream) {
    const float* Q     = (const float*)d_in[0];
    const float* K     = (const float*)d_in[1];
    const float* V     = (const float*)d_in[2];
    const float* tau   = (const float*)d_in[3];
    const float* delta = (const float*)d_in[4];
    float* out = (float*)d_out;

    const size_t elems = (size_t)Bb * Hh * Ss * Ee;            // 4M per tensor
    const size_t need  = elems * 2 * 2 + (size_t)Bb * Ss * 4;  // K16 + VT16 + delta2

    if (ws_size >= need) {
        _Float16* K16    = (_Float16*)d_ws;
        _Float16* VT16   = K16 + elems;
        float*    delta2 = (float*)(VT16 + elems);
        hipLaunchKernelGGL(prepass_k, dim3(elems / 4 / 256), dim3(256), 0, stream,
                           K, K16, delta, delta2);
        hipLaunchKernelGGL(prepass_v, dim3(Ss / 64, Bb * Hh), dim3(256), 0, stream, V, VT16);
        hipLaunchKernelGGL(dsattn_fwd_v8, dim3(512), dim3(512), 65536, stream,
                           Q, K16, VT16, tau, delta2, out);
    } else {
        hipLaunchKernelGGL(dsattn_fwd, dim3(Ll / 64, Bb * Hh), dim3(256), 0, stream,
                           Q, K, V, tau, delta, out);
    }
}